// Round 11
// baseline (186.431 us; speedup 1.0000x reference)
//
#include <hip/hip_runtime.h>
#include <hip/hip_bf16.h>
#include <math.h>

// Problem constants
#define BB   32
#define HN   12
#define N1   256
#define N2   320
#define SS   256
#define BH   (BB*HN)                 // 384
#define R4   (N2/4)                  // 80 float4 per row
#define SLICE4 ((size_t)N1*R4)       // f4 per (b,h) per tensor = 20480

#define AGENT __HIP_MEMORY_SCOPE_AGENT

typedef float v4f __attribute__((ext_vector_type(4)));

// 768 blocks x 256 threads = exactly 3 blocks/CU, all co-resident.
// Pair (bh,0)/(bh,1): each owns half the (b,h) slice (rows 0-127 / 128-255,
// both tensors). Handoff via relaxed agent-scope atomics (MALL-coherent,
// no L2-invalidating fences) + one release/acquire flag per direction.
__global__ __launch_bounds__(256, 3) void k_pair(
    const float* __restrict__ rgb, const float* __restrict__ tir,
    const int*   __restrict__ gidx,
    const float* __restrict__ ln_g, const float* __restrict__ ln_b,
    const float* __restrict__ W1,  const float* __restrict__ b1,
    const float* __restrict__ W2,  const float* __restrict__ b2,
    unsigned* __restrict__ flagA, unsigned* __restrict__ flagB,
    float* __restrict__ mx_g,     // [BH][2*256]  (tensor*256 + row)
    float* __restrict__ grow_g,   // [BH][256]    gathered gates, rows 128-255
    v4f* __restrict__ outTir, v4f* __restrict__ outRgb)
{
    __shared__ float v[2 * SS];
    __shared__ float hs[SS];
    __shared__ float gs[2 * SS];
    __shared__ int   sidx_s[SS];
    __shared__ float red[8];
    __shared__ float growR[128];   // gates for this block's 128 rows
    __shared__ float growT[128];

    const int j    = (int)blockIdx.x;    // 0..767
    const int bh   = j >> 1;
    const int half = j & 1;
    const int b    = bh / HN;
    const int t    = (int)threadIdx.x;   // 0..255
    const int w    = t >> 6;
    const int lane = t & 63;
    const int row0 = half * 128;

    const float* sliceR = rgb + (size_t)bh * (N1 * N2);
    const float* sliceT = tir + (size_t)bh * (N1 * N2);

    // ---- Phase A: rowmax for rows [row0,row0+128) of both tensors ----
    // 256 row-units: u = tensor*128 + (row-row0); wave w owns [w*64,w*64+64).
    {
        float* mxout = mx_g + bh * 512;
        for (int uu = 0; uu < 64; uu += 8) {
            const int u0 = w * 64 + uu;
            v4f a[8], b8[8];
#pragma unroll
            for (int q = 0; q < 8; ++q) {
                int u   = u0 + q;
                int row = row0 + (u & 127);
                const v4f* p = (const v4f*)((u >= 128 ? sliceT : sliceR)
                                            + (size_t)row * N2);
                a[q]  = p[lane];
                // tail f4s [64,80): lane-duplicated (no effect on max)
                b8[q] = p[64 + (lane & 15)];
            }
#pragma unroll
            for (int q = 0; q < 8; ++q) {
                float m = fmaxf(fmaxf(fmaxf(a[q].x, a[q].y), fmaxf(a[q].z, a[q].w)),
                                fmaxf(fmaxf(b8[q].x, b8[q].y), fmaxf(b8[q].z, b8[q].w)));
#pragma unroll
                for (int off = 32; off; off >>= 1) m = fmaxf(m, __shfl_xor(m, off));
                if (lane == 0) {
                    int u = u0 + q;
                    __hip_atomic_store(&mxout[(u >> 7) * 256 + row0 + (u & 127)],
                                       m, __ATOMIC_RELAXED, AGENT);
                }
            }
        }
    }
    __syncthreads();                     // all maxes issued + vmcnt drained
    if (t == 0) __hip_atomic_fetch_add(&flagA[bh], 1u, __ATOMIC_RELEASE, AGENT);

    if (half == 0) {
        // ---- wait for sibling's maxes ----
        if (t == 0) {
            while (__hip_atomic_load(&flagA[bh], __ATOMIC_RELAXED, AGENT) < 2u)
                __builtin_amdgcn_s_sleep(4);
            (void)__hip_atomic_load(&flagA[bh], __ATOMIC_ACQUIRE, AGENT);
        }
        __syncthreads();

        // ---- MLP: scatter -> LN(512) -> GEMM1 relu -> GEMM2 sigmoid ----
        sidx_s[t] = gidx[b * SS + t];
        float mR = __hip_atomic_load(&mx_g[bh * 512 + t],       __ATOMIC_RELAXED, AGENT);
        float mT = __hip_atomic_load(&mx_g[bh * 512 + 256 + t], __ATOMIC_RELAXED, AGENT);
        v[t] = 0.f; v[t + SS] = 0.f;
        __syncthreads();
        v[sidx_s[t]]      = mR;
        v[sidx_s[t] + SS] = mT;
        __syncthreads();

        {   // LayerNorm over 512
            float x0 = v[t], x1 = v[t + SS];
            float s  = x0 + x1;
            float sq = x0 * x0 + x1 * x1;
#pragma unroll
            for (int off = 32; off; off >>= 1) {
                s  += __shfl_xor(s, off);
                sq += __shfl_xor(sq, off);
            }
            if (lane == 0) { red[w] = s; red[4 + w] = sq; }
            __syncthreads();
            s  = red[0] + red[1] + red[2] + red[3];
            sq = red[4] + red[5] + red[6] + red[7];
            const float mu   = s * (1.f / 512.f);
            const float var  = sq * (1.f / 512.f) - mu * mu;
            const float rstd = rsqrtf(var + 1e-5f);
            v[t]      = (x0 - mu) * rstd * ln_g[t]      + ln_b[t];
            v[t + SS] = (x1 - mu) * rstd * ln_g[t + SS] + ln_b[t + SS];
        }
        __syncthreads();

        {   // GEMM1: hs[t] = relu(sum_e v[e]*W1[e*256+t] + b1[t])
            float a0 = b1[t], a1 = 0.f;
#pragma unroll 8
            for (int e = 0; e < SS; ++e)       a0 = fmaf(v[e], W1[e * SS + t], a0);
#pragma unroll 8
            for (int e = SS; e < 2 * SS; ++e)  a1 = fmaf(v[e], W1[e * SS + t], a1);
            hs[t] = fmaxf(a0 + a1, 0.f);
        }
        __syncthreads();

        {   // GEMM2: gs[t], gs[t+256] = sigmoid(sum_f hs[f]*W2[f*512+.] + b2)
            float lo0 = b2[t], lo1 = 0.f, hi0 = b2[t + SS], hi1 = 0.f;
#pragma unroll 8
            for (int f = 0; f < 128; ++f) {
                float hv = hs[f];
                lo0 = fmaf(hv, W2[f * 2 * SS + t],      lo0);
                hi0 = fmaf(hv, W2[f * 2 * SS + t + SS], hi0);
            }
#pragma unroll 8
            for (int f = 128; f < SS; ++f) {
                float hv = hs[f];
                lo1 = fmaf(hv, W2[f * 2 * SS + t],      lo1);
                hi1 = fmaf(hv, W2[f * 2 * SS + t + SS], hi1);
            }
            gs[t]      = 1.f / (1.f + expf(-(lo0 + lo1)));
            gs[t + SS] = 1.f / (1.f + expf(-(hi0 + hi1)));
        }
        __syncthreads();

        // gather per-row gates; keep rows 0-127 in LDS, publish rows 128-255
        {
            int s = sidx_s[t];
            float gR = gs[s], gT = gs[s + SS];
            if (t < 128) { growR[t] = gR; growT[t] = gT; }
            else {
                __hip_atomic_store(&grow_g[bh * 256 + (t - 128)],       gR,
                                   __ATOMIC_RELAXED, AGENT);
                __hip_atomic_store(&grow_g[bh * 256 + 128 + (t - 128)], gT,
                                   __ATOMIC_RELAXED, AGENT);
            }
        }
        __syncthreads();
        if (t == 0) __hip_atomic_fetch_add(&flagB[bh], 1u, __ATOMIC_RELEASE, AGENT);
    } else {
        // ---- wait for gates ----
        if (t == 0) {
            while (__hip_atomic_load(&flagB[bh], __ATOMIC_RELAXED, AGENT) < 1u)
                __builtin_amdgcn_s_sleep(4);
            (void)__hip_atomic_load(&flagB[bh], __ATOMIC_ACQUIRE, AGENT);
        }
        __syncthreads();
        if (t < 128) {
            growR[t] = __hip_atomic_load(&grow_g[bh * 256 + t],       __ATOMIC_RELAXED, AGENT);
            growT[t] = __hip_atomic_load(&grow_g[bh * 256 + 128 + t], __ATOMIC_RELAXED, AGENT);
        }
        __syncthreads();
    }

    // ---- Phase C: modulate rows [row0,row0+128), both tensors; NT stores --
    // Re-read is L3-hot (FETCH stayed 250MB in R6/R9/R10). 16 loads in flight.
    {
        const v4f* sR4 = (const v4f*)sliceR;
        const v4f* sT4 = (const v4f*)sliceT;
        v4f* dR = outRgb + (size_t)bh * SLICE4;
        v4f* dT = outTir + (size_t)bh * SLICE4;
        const unsigned base = (unsigned)row0 * 80u;
        for (int k = 0; k < 40; k += 8) {     // 128 rows * 80 f4 = 40*256
            v4f aR[8], aT[8]; float gR[8], gT[8];
#pragma unroll
            for (int q = 0; q < 8; ++q) {
                unsigned i = base + (unsigned)(k + q) * 256u + (unsigned)t;
                aR[q] = sR4[i];
                aT[q] = sT4[i];
                unsigned lr = (i / 80u) - (unsigned)row0;   // 0..127
                gR[q] = growR[lr];
                gT[q] = growT[lr];
            }
#pragma unroll
            for (int q = 0; q < 8; ++q) {
                unsigned i = base + (unsigned)(k + q) * 256u + (unsigned)t;
                __builtin_nontemporal_store(aT[q] * gT[q], dT + i);
                __builtin_nontemporal_store(aR[q] * gR[q], dR + i);
            }
        }
    }
}

extern "C" void kernel_launch(void* const* d_in, const int* in_sizes, int n_in,
                              void* d_out, int out_size, void* d_ws, size_t ws_size,
                              hipStream_t stream)
{
    const float* attn_rgb = (const float*)d_in[0];
    const float* attn_tir = (const float*)d_in[1];
    const int*   gidx     = (const int*)  d_in[2];
    const float* ln_g     = (const float*)d_in[3];
    const float* ln_b     = (const float*)d_in[4];
    const float* W1       = (const float*)d_in[5];
    const float* b1       = (const float*)d_in[6];
    const float* W2       = (const float*)d_in[7];
    const float* b2       = (const float*)d_in[8];

    // Workspace: [0,4K) flagA, [4K,8K) flagB, then mx_g and grow_g.
    unsigned* flagA = (unsigned*)d_ws;
    unsigned* flagB = (unsigned*)((char*)d_ws + 4096);
    float*    mx_g  = (float*)((char*)d_ws + 8192);            // 384*512*4 = 768KB
    float*    grow_g = mx_g + (size_t)BH * 512;                // 384*256*4 = 384KB

    v4f* outTir = (v4f*)d_out;               // tir_col first per reference
    v4f* outRgb = outTir + (size_t)BH * SLICE4;

    // Zero the flags each call (graph-capture-safe async memset node).
    hipMemsetAsync(d_ws, 0, 8192, stream);

    k_pair<<<2 * BH, 256, 0, stream>>>(attn_rgb, attn_tir, gidx, ln_g, ln_b,
                                       W1, b1, W2, b2, flagA, flagB,
                                       mx_g, grow_g, outTir, outRgb);
}

// Round 12
// 172.459 us; speedup vs baseline: 1.0810x; 1.0810x over previous
//
#include <hip/hip_runtime.h>
#include <math.h>

// Problem constants
#define BB   32
#define HN   12
#define N1   256
#define N2   320
#define SS   256
#define BH   (BB*HN)                 // 384
#define R4   (N2/4)                  // 80 float4 per row
#define SLICE4 ((size_t)N1*R4)       // f4 per (b,h) per tensor = 20480

typedef float v4f __attribute__((ext_vector_type(4)));

// 768 blocks x 256 threads = uniform 3 blocks/CU, ZERO inter-block sync.
// Pair (bh,0)/(bh,1): both read the full (b,h) slice (opposite directions ->
// each line HBM-fetched once, sibling hits cache), both compute all 512 row
// maxes + the full MLP redundantly in LDS/registers, then each modulates its
// own half of the rows (disjoint output). No workspace, no atomics, no flags.
__global__ __launch_bounds__(256, 3) void k_pair(
    const float* __restrict__ rgb, const float* __restrict__ tir,
    const int*   __restrict__ gidx,
    const float* __restrict__ ln_g, const float* __restrict__ ln_b,
    const float* __restrict__ W1,  const float* __restrict__ b1,
    const float* __restrict__ W2,  const float* __restrict__ b2,
    v4f* __restrict__ outTir, v4f* __restrict__ outRgb)
{
    __shared__ float mxs[2 * SS];    // all row maxes: rgb [0,256), tir [256,512)
    __shared__ float v[2 * SS];      // scattered -> normalized vector
    __shared__ float hs[SS];         // hidden relu
    __shared__ float gs[2 * SS];     // sigmoid gates
    __shared__ int   sidx_s[SS];
    __shared__ float red[8];
    __shared__ float growR[128];     // gates for this block's own 128 rows
    __shared__ float growT[128];

    const int j    = (int)blockIdx.x;    // 0..767
    const int bh   = j >> 1;
    const int half = j & 1;
    const int b    = bh / HN;
    const int t    = (int)threadIdx.x;   // 0..255
    const int w    = t >> 6;
    const int lane = t & 63;

    sidx_s[t] = gidx[b * SS + t];
    v[t] = 0.f; v[t + SS] = 0.f;

    const float* sliceR = rgb + (size_t)bh * (N1 * N2);
    const float* sliceT = tir + (size_t)bh * (N1 * N2);

    // ---- Phase A: ALL 512 row-units (tensor*256+row); wave w owns 128.
    // half=1 traverses reversed so the pair sweeps the slice from both ends:
    // every line is fetched once and cache-hit by the sibling shortly after.
    for (int uu = 0; uu < 128; uu += 8) {
        v4f a[8], b8[8];
#pragma unroll
        for (int q = 0; q < 8; ++q) {
            int lin = w * 128 + uu + q;
            int u   = half ? 511 - lin : lin;
            const v4f* p = (const v4f*)((u >= SS ? sliceT : sliceR)
                                        + (size_t)(u & 255) * N2);
            a[q]  = p[lane];
            // tail f4s [64,80): lane-duplicated (no effect on max; duplicate
            // addresses coalesce to the same cache lines)
            b8[q] = p[64 + (lane & 15)];
        }
#pragma unroll
        for (int q = 0; q < 8; ++q) {
            float m = fmaxf(fmaxf(fmaxf(a[q].x, a[q].y), fmaxf(a[q].z, a[q].w)),
                            fmaxf(fmaxf(b8[q].x, b8[q].y), fmaxf(b8[q].z, b8[q].w)));
#pragma unroll
            for (int off = 32; off; off >>= 1) m = fmaxf(m, __shfl_xor(m, off));
            if (lane == 0) {
                int lin = w * 128 + uu + q;
                mxs[half ? 511 - lin : lin] = m;
            }
        }
    }
    __syncthreads();

    // ---- Phase B (redundant per pair): scatter -> LN -> GEMM1 -> GEMM2 ----
    {
        int sidx = sidx_s[t];
        v[sidx]      = mxs[t];
        v[sidx + SS] = mxs[SS + t];
    }
    __syncthreads();

    {   // LayerNorm over 512
        float x0 = v[t], x1 = v[t + SS];
        float s  = x0 + x1;
        float sq = x0 * x0 + x1 * x1;
#pragma unroll
        for (int off = 32; off; off >>= 1) {
            s  += __shfl_xor(s, off);
            sq += __shfl_xor(sq, off);
        }
        if (lane == 0) { red[w] = s; red[4 + w] = sq; }
        __syncthreads();
        s  = red[0] + red[1] + red[2] + red[3];
        sq = red[4] + red[5] + red[6] + red[7];
        const float mu   = s * (1.f / 512.f);
        const float var  = sq * (1.f / 512.f) - mu * mu;
        const float rstd = rsqrtf(var + 1e-5f);
        v[t]      = (x0 - mu) * rstd * ln_g[t]      + ln_b[t];
        v[t + SS] = (x1 - mu) * rstd * ln_g[t + SS] + ln_b[t + SS];
    }
    __syncthreads();

    {   // GEMM1: hs[t] = relu(sum_e v[e]*W1[e*256+t] + b1[t])
        float a0 = b1[t], a1 = 0.f;
#pragma unroll 8
        for (int e = 0; e < SS; ++e)       a0 = fmaf(v[e], W1[e * SS + t], a0);
#pragma unroll 8
        for (int e = SS; e < 2 * SS; ++e)  a1 = fmaf(v[e], W1[e * SS + t], a1);
        hs[t] = fmaxf(a0 + a1, 0.f);
    }
    __syncthreads();

    {   // GEMM2: gs[t], gs[t+256] = sigmoid(sum_f hs[f]*W2[f*512+.] + b2)
        float lo0 = b2[t], lo1 = 0.f, hi0 = b2[t + SS], hi1 = 0.f;
#pragma unroll 8
        for (int f = 0; f < 128; ++f) {
            float hv = hs[f];
            lo0 = fmaf(hv, W2[f * 2 * SS + t],      lo0);
            hi0 = fmaf(hv, W2[f * 2 * SS + t + SS], hi0);
        }
#pragma unroll 8
        for (int f = 128; f < SS; ++f) {
            float hv = hs[f];
            lo1 = fmaf(hv, W2[f * 2 * SS + t],      lo1);
            hi1 = fmaf(hv, W2[f * 2 * SS + t + SS], hi1);
        }
        gs[t]      = 1.f / (1.f + expf(-(lo0 + lo1)));
        gs[t + SS] = 1.f / (1.f + expf(-(hi0 + hi1)));
    }
    __syncthreads();

    // gather gates for OWN half rows only
    if (t < 128) {
        int s = sidx_s[half * 128 + t];
        growR[t] = gs[s];
        growT[t] = gs[s + SS];
    }
    __syncthreads();

    // ---- Phase C: modulate own rows [half*128, half*128+128), both tensors.
    // These lines were touched LAST by the sibling's phase A -> MALL-fresh.
    {
        const v4f* sR4 = (const v4f*)sliceR;
        const v4f* sT4 = (const v4f*)sliceT;
        v4f* dR = outRgb + (size_t)bh * SLICE4;
        v4f* dT = outTir + (size_t)bh * SLICE4;
        const unsigned base = (unsigned)(half * 128) * 80u;   // f4 offset
        for (int k = 0; k < 80; k += 8) {                     // 20480 f4 flat
            v4f a[8]; float g[8];
#pragma unroll
            for (int q = 0; q < 8; ++q) {
                unsigned i  = (unsigned)(k + q) * 256u + (unsigned)t; // 0..20479
                int isRgb   = i >= 10240u;
                unsigned jj = isRgb ? i - 10240u : i;                 // 0..10239
                a[q] = (isRgb ? sR4 : sT4)[base + jj];
                g[q] = (isRgb ? growR : growT)[jj / 80u];
            }
#pragma unroll
            for (int q = 0; q < 8; ++q) {
                unsigned i  = (unsigned)(k + q) * 256u + (unsigned)t;
                int isRgb   = i >= 10240u;
                unsigned jj = isRgb ? i - 10240u : i;
                __builtin_nontemporal_store(a[q] * g[q],
                                            (isRgb ? dR : dT) + base + jj);
            }
        }
    }
}

extern "C" void kernel_launch(void* const* d_in, const int* in_sizes, int n_in,
                              void* d_out, int out_size, void* d_ws, size_t ws_size,
                              hipStream_t stream)
{
    const float* attn_rgb = (const float*)d_in[0];
    const float* attn_tir = (const float*)d_in[1];
    const int*   gidx     = (const int*)  d_in[2];
    const float* ln_g     = (const float*)d_in[3];
    const float* ln_b     = (const float*)d_in[4];
    const float* W1       = (const float*)d_in[5];
    const float* b1       = (const float*)d_in[6];
    const float* W2       = (const float*)d_in[7];
    const float* b2       = (const float*)d_in[8];

    v4f* outTir = (v4f*)d_out;               // tir_col first per reference
    v4f* outRgb = outTir + (size_t)BH * SLICE4;

    k_pair<<<2 * BH, 256, 0, stream>>>(attn_rgb, attn_tir, gidx, ln_g, ln_b,
                                       W1, b1, W2, b2, outTir, outRgb);
}

// Round 13
// 142.891 us; speedup vs baseline: 1.3047x; 1.2069x over previous
//
#include <hip/hip_runtime.h>
#include <math.h>

// Problem constants
#define BB   32
#define HN   12
#define N1   256
#define N2   320
#define SS   256
#define BH   (BB*HN)                 // 384
#define R4   (N2/4)                  // 80 float4 per row
#define SLICE4 ((size_t)N1*R4)       // f4 per (b,h) per tensor = 20480

typedef float v4f __attribute__((ext_vector_type(4)));

// One block of 512 threads (8 waves) per (b,h). No inter-block sync, no
// global workspace. launch_bounds(512,4) -> 2 blocks/CU, VGPR cap 128.
//  Phase A: read own slice, 512 row-maxes -> LDS (8-deep load batches).
//  Phase B: scatter -> LN(512) -> GEMM1(relu) -> GEMM2(sigmoid), with
//           float4 weight loads (4 outputs/thread, K-split across waves).
//  Phase C: re-read own slice (MALL-hot), scale, NT-store.
__global__ __launch_bounds__(512, 4) void k_fused(
    const float* __restrict__ rgb, const float* __restrict__ tir,
    const int*   __restrict__ gidx,
    const float* __restrict__ ln_g, const float* __restrict__ ln_b,
    const float* __restrict__ W1,  const float* __restrict__ b1,
    const float* __restrict__ W2,  const float* __restrict__ b2,
    v4f* __restrict__ outTir, v4f* __restrict__ outRgb)
{
    __shared__ float mxs[2 * SS];    // row maxes: rgb [0,256), tir [256,512)
    __shared__ float v[2 * SS];      // scattered -> normalized vector
    __shared__ float h8[8][SS];      // GEMM1 K-segment partials
    __shared__ float hs[SS];         // hidden relu
    __shared__ float g8[4][2 * SS];  // GEMM2 K-segment partials
    __shared__ float gs[2 * SS];     // sigmoid gates
    __shared__ float growR[SS];      // per-row gate, rgb
    __shared__ float growT[SS];      // per-row gate, tir
    __shared__ int   sidx_s[SS];
    __shared__ float red[16];

    const int bh   = (int)blockIdx.x;    // 0..383
    const int b    = bh / HN;
    const int t    = (int)threadIdx.x;   // 0..511
    const int w    = t >> 6;             // wave 0..7
    const int lane = t & 63;

    if (t < SS) sidx_s[t] = gidx[b * SS + t];
    v[t] = 0.f;

    const float* sliceR = rgb + (size_t)bh * (N1 * N2);
    const float* sliceT = tir + (size_t)bh * (N1 * N2);

    // ---- Phase A: 512 row-units (tensor*256+row); wave w owns 64; 8-deep --
    for (int uu = 0; uu < 64; uu += 8) {
        const int u0 = w * 64 + uu;
        v4f a[8], b8[8];
#pragma unroll
        for (int q = 0; q < 8; ++q) {
            int u   = u0 + q;
            const v4f* p = (const v4f*)((u >= SS ? sliceT : sliceR)
                                        + (size_t)(u & 255) * N2);
            a[q]  = p[lane];
            // tail f4s [64,80): lane-duplicated (no effect on max; duplicate
            // addresses coalesce)
            b8[q] = p[64 + (lane & 15)];
        }
#pragma unroll
        for (int q = 0; q < 8; ++q) {
            float m = fmaxf(fmaxf(fmaxf(a[q].x, a[q].y), fmaxf(a[q].z, a[q].w)),
                            fmaxf(fmaxf(b8[q].x, b8[q].y), fmaxf(b8[q].z, b8[q].w)));
#pragma unroll
            for (int off = 32; off; off >>= 1) m = fmaxf(m, __shfl_xor(m, off));
            if (lane == 0) mxs[u0 + q] = m;
        }
    }
    __syncthreads();

    // ---- Phase B1: scatter (per-batch permutation -> collision-free) ----
    if (t < SS) {
        int sidx = sidx_s[t];
        v[sidx]      = mxs[t];
        v[sidx + SS] = mxs[t + SS];
    }
    __syncthreads();

    // ---- Phase B2: LayerNorm over 512 (one element per thread) ----
    {
        float x  = v[t];
        float s  = x;
        float sq = x * x;
#pragma unroll
        for (int off = 32; off; off >>= 1) {
            s  += __shfl_xor(s, off);
            sq += __shfl_xor(sq, off);
        }
        if (lane == 0) { red[w] = s; red[8 + w] = sq; }
        __syncthreads();
        s  = red[0] + red[1] + red[2] + red[3] + red[4] + red[5] + red[6] + red[7];
        sq = red[8] + red[9] + red[10] + red[11] + red[12] + red[13] + red[14] + red[15];
        const float mu   = s * (1.f / 512.f);
        const float var  = sq * (1.f / 512.f) - mu * mu;
        const float rstd = rsqrtf(var + 1e-5f);
        v[t] = (x - mu) * rstd * ln_g[t] + ln_b[t];
    }
    __syncthreads();

    // ---- Phase B3: GEMM1, float4 weights. Wave w = K-chunk [w*64,w*64+64),
    // lane -> outputs 4*lane..4*lane+3. 64 iters of one f4 load + 4 fma.
    {
        const int e0 = w * 64;
        v4f acc = {0.f, 0.f, 0.f, 0.f};
#pragma unroll 8
        for (int e = 0; e < 64; ++e) {
            v4f wv = *(const v4f*)&W1[(size_t)(e0 + e) * SS + 4 * lane];
            acc += wv * v[e0 + e];
        }
        *(v4f*)&h8[w][4 * lane] = acc;
    }
    __syncthreads();
    if (t < SS) {
        float a = b1[t];
#pragma unroll
        for (int s = 0; s < 8; ++s) a += h8[s][t];
        hs[t] = fmaxf(a, 0.f);
    }
    __syncthreads();

    // ---- Phase B4: GEMM2, float4 weights. fs = w>>1 (K-chunk of 64),
    // half = w&1 -> output quads [half*256 .. ) : lane covers 64 quads.
    // outputs 4*(half*64+lane) .. +3  (i.e. 256 outputs per half).
    {
        const int fs   = w >> 1;           // 0..3
        const int oq   = (w & 1) * 64 + lane;  // output quad 0..127
        const int f0   = fs * 64;
        v4f acc = {0.f, 0.f, 0.f, 0.f};
#pragma unroll 8
        for (int f = 0; f < 64; ++f) {
            v4f wv = *(const v4f*)&W2[(size_t)(f0 + f) * (2 * SS) + 4 * oq];
            acc += wv * hs[f0 + f];
        }
        *(v4f*)&g8[fs][4 * oq] = acc;
    }
    __syncthreads();
    {
        float a = b2[t] + g8[0][t] + g8[1][t] + g8[2][t] + g8[3][t];
        gs[t] = 1.f / (1.f + expf(-a));
    }
    __syncthreads();

    // ---- Phase B5: gather per-row gates ----
    if (t < SS) {
        growR[t] = gs[sidx_s[t]];
        growT[t] = gs[sidx_s[t] + SS];
    }
    __syncthreads();

    // ---- Phase C: hot re-read own slice, scale, NT-store ----
    // 40960 f4 (both tensors), flat: i = k*512 + t; tir first half.
    {
        const v4f* srcR4 = (const v4f*)sliceR;
        const v4f* srcT4 = (const v4f*)sliceT;
        v4f* dstR = outRgb + (size_t)bh * SLICE4;
        v4f* dstT = outTir + (size_t)bh * SLICE4;
        for (int k = 0; k < 80; k += 8) {
            v4f a[8]; float g[8];
#pragma unroll
            for (int q = 0; q < 8; ++q) {
                unsigned i = (unsigned)(k + q) * 512u + (unsigned)t;  // < 40960
                int isRgb  = i >= 20480u;
                unsigned j = isRgb ? i - 20480u : i;
                a[q] = isRgb ? srcR4[j] : srcT4[j];
                g[q] = (isRgb ? growR : growT)[j / 80u];
            }
#pragma unroll
            for (int q = 0; q < 8; ++q) {
                unsigned i = (unsigned)(k + q) * 512u + (unsigned)t;
                int isRgb  = i >= 20480u;
                unsigned j = isRgb ? i - 20480u : i;
                __builtin_nontemporal_store(a[q] * g[q],
                                            (isRgb ? dstR : dstT) + j);
            }
        }
    }
}

extern "C" void kernel_launch(void* const* d_in, const int* in_sizes, int n_in,
                              void* d_out, int out_size, void* d_ws, size_t ws_size,
                              hipStream_t stream)
{
    const float* attn_rgb = (const float*)d_in[0];
    const float* attn_tir = (const float*)d_in[1];
    const int*   gidx     = (const int*)  d_in[2];
    const float* ln_g     = (const float*)d_in[3];
    const float* ln_b     = (const float*)d_in[4];
    const float* W1       = (const float*)d_in[5];
    const float* b1       = (const float*)d_in[6];
    const float* W2       = (const float*)d_in[7];
    const float* b2       = (const float*)d_in[8];

    v4f* outTir = (v4f*)d_out;               // tir_col first per reference
    v4f* outRgb = outTir + (size_t)BH * SLICE4;

    k_fused<<<BH, 512, 0, stream>>>(attn_rgb, attn_tir, gidx, ln_g, ln_b,
                                    W1, b1, W2, b2, outTir, outRgb);
}